// Round 7
// baseline (247.849 us; speedup 1.0000x reference)
//
#include <hip/hip_runtime.h>

typedef __bf16 bf16x8 __attribute__((ext_vector_type(8)));
typedef float floatx4 __attribute__((ext_vector_type(4)));

#define NCH 128  // number of time chunks
#define CLEN 16  // chunk length (NCH*CLEN = 2048)

__device__ __forceinline__ unsigned short f2bf(float f) {
  unsigned int u = __builtin_bit_cast(unsigned int, f);
  u += 0x7fff + ((u >> 16) & 1);
  return (unsigned short)(u >> 16);
}
__device__ __forceinline__ float bf2f(unsigned short u) {
  unsigned int v = (unsigned int)u << 16;
  return __builtin_bit_cast(float, v);
}
__device__ __forceinline__ float bf2f_lo(unsigned int u) {
  return __builtin_bit_cast(float, u << 16);
}
__device__ __forceinline__ float bf2f_hi(unsigned int u) {
  return __builtin_bit_cast(float, u & 0xffff0000u);
}

// async 16B global->LDS copy; LDS dest = wave-uniform base + lane*16
__device__ __forceinline__ void async_copy16(const void* g, void* l) {
  __builtin_amdgcn_global_load_lds(
      (const __attribute__((address_space(1))) unsigned int*)g,
      (__attribute__((address_space(3))) unsigned int*)l, 16, 0, 0);
}

// ---------------- casts ----------------
__global__ void cast_x_kernel(const float* __restrict__ in, unsigned short* __restrict__ out) {
  int i = blockIdx.x * blockDim.x + threadIdx.x;  // exact: 8192 blk * 256 thr * 4 elems
  float4 v = ((const float4*)in)[i];
  ushort4 o;
  o.x = f2bf(v.x); o.y = f2bf(v.y); o.z = f2bf(v.z); o.w = f2bf(v.w);
  ((ushort4*)out)[i] = o;
}

// both weights: W (1024 x ncols) fp32 -> WT (ncols x 1024) bf16, one launch
__global__ void tcast2_kernel(const float* __restrict__ Win, unsigned short* __restrict__ winT,
                              const float* __restrict__ Wout, unsigned short* __restrict__ woutT) {
  __shared__ float tile[32][33];
  int bx = blockIdx.x;
  const float* W;
  unsigned short* WT;
  int ncols, n0;
  if (bx < 96) { W = Win; WT = winT; ncols = 3072; n0 = bx * 32; }
  else { W = Wout; WT = woutT; ncols = 1024; n0 = (bx - 96) * 32; }
  int k0 = blockIdx.y * 32;
  int tx = threadIdx.x, ty = threadIdx.y;
  tile[ty][tx] = W[(size_t)(k0 + ty) * ncols + n0 + tx];
  __syncthreads();
  WT[(size_t)(n0 + ty) * 1024 + k0 + tx] = f2bf(tile[tx][ty]);
}

// ---------------- unified GEMM: 128x256 tile, triple-buffered, R6 schedule ----------------
// BM=128, BN=256, BK=64, 512 thr (2x4 waves, 64x64 out/wave).
// EPI==1 (gemm1): grid 768 = 64m x 12n (= 3 x 256 CUs, zero tail);
//                 activation epilogue -> bf16 silu/sigmoid/om segments.
// EPI==0 (gemm2): grid 256 = 64m x 4n (= 1.0 blocks/CU, zero tail);
//                 bias epilogue -> fp32 out.
// LDS 144KB: A x3 (16KB) @ 0/16384/32768; B x3 (32KB) @ 49152/81920/114688.
// Tile t reads buf t%3; stages tile t+2 into buf (t+2)%3 (WAR-safe by
// rotation). 6 staging instrs/thread/tile -> steady vmcnt(6) once per tile.
template <int EPI>
__global__ __launch_bounds__(512, 2) void gemm1_kernel(
    const unsigned short* __restrict__ A, const unsigned short* __restrict__ BT,
    const float* __restrict__ bias, const float* __restrict__ lb,
    float* __restrict__ outf,
    unsigned short* __restrict__ o_inp, unsigned short* __restrict__ o_og,
    unsigned short* __restrict__ o_om) {
  __shared__ alignas(16) char smem[147456];
  // XCD-aware bijective swizzle (m-fast: best measured).
  const int orig = blockIdx.x;
  const int wg = (EPI == 1) ? (orig & 7) * 96 + (orig >> 3)   // 768 = 8 x 96
                            : (orig & 7) * 32 + (orig >> 3);  // 256 = 8 x 32
  const int m0 = (wg & 63) << 7;  // 64 m-tiles of 128 (fast -> share B panel)
  const int n0 = (wg >> 6) << 8;  // 12 (EPI=1) / 4 (EPI=0) n-tiles of 256
  const int tid = threadIdx.x;
  const int lane = tid & 63, wave = tid >> 6;
  const int wm = wave >> 2, wn = wave & 3;
  // staging: thread covers LDS slot (row=tid>>3, chunk=tid&7); fetch global
  // chunk (tid&7)^(row&7) so linear global_load_lds realizes the swizzle
  const int srow = tid >> 3;
  const int sq = (tid & 7) ^ (srow & 7);
  const unsigned short* gA = A + (size_t)(m0 + srow) * 1024 + sq * 8;
  const unsigned short* gB = BT + (size_t)(n0 + srow) * 1024 + sq * 8;
  char* lw = smem + wave * 1024;  // wave-uniform LDS slot base
  // ds_read: row r at byte r*128; chunk q at (q^(r&7))*16; r&7 == lane&7 here
  const int aro = (wm * 64 + (lane & 15)) * 128;
  const int bro = (wn * 64 + (lane & 15)) * 128;
  const int qs0 = ((lane >> 4) ^ (lane & 7)) * 16;        // k-step 0 (k 0..31)
  const int qs1 = ((4 + (lane >> 4)) ^ (lane & 7)) * 16;  // k-step 1 (k 32..63)

  floatx4 acc[4][4] = {};
  bf16x8 aF[4][2], bF[4][2];

#define STG(lofs, gh, kk)                                \
  do {                                                   \
    const unsigned short* _g = (gh) + (size_t)(kk) * 64; \
    async_copy16(_g, lw + (lofs));                       \
    async_copy16(_g + 65536, lw + (lofs) + 8192);        \
  } while (0)
#define RA(base, i, s) \
  (*(const bf16x8*)(smem + (base) + aro + (i) * 2048 + ((s) ? qs1 : qs0)))
#define RB(base, j, s) \
  (*(const bf16x8*)(smem + (base) + bro + (j) * 2048 + ((s) ? qs1 : qs0)))
#define BAR __builtin_amdgcn_s_barrier()
#define LGKM0 asm volatile("s_waitcnt lgkmcnt(0)" ::: "memory")
#define VM6 asm volatile("s_waitcnt vmcnt(6)" ::: "memory")
#define MM(d, a, b) d = __builtin_amdgcn_mfma_f32_16x16x32_bf16(a, b, d, 0, 0, 0)

// One K-tile: Phase A (A reads + B01 + stage A[t+2],B[t+2]h0 -> MFMA j01),
// Phase B (B23 reads + stage B[t+2]h1 -> MFMA j23, vmcnt(6)).
#define TILE(AB, BB, SA, SB, kk)                                               \
  do {                                                                         \
    _Pragma("unroll") for (int i = 0; i < 4; i++) {                            \
      aF[i][0] = RA(AB, i, 0); aF[i][1] = RA(AB, i, 1);                        \
    }                                                                          \
    _Pragma("unroll") for (int j = 0; j < 2; j++) {                            \
      bF[j][0] = RB(BB, j, 0); bF[j][1] = RB(BB, j, 1);                        \
    }                                                                          \
    STG(SA, gA, kk);                                                           \
    STG(SB, gB, kk);                                                           \
    BAR; LGKM0;                                                                \
    __builtin_amdgcn_s_setprio(1);                                             \
    _Pragma("unroll") for (int i = 0; i < 4; i++) {                            \
      _Pragma("unroll") for (int j = 0; j < 2; j++) {                          \
        MM(acc[i][j], aF[i][0], bF[j][0]); MM(acc[i][j], aF[i][1], bF[j][1]);  \
      }                                                                        \
    }                                                                          \
    __builtin_amdgcn_s_setprio(0);                                             \
    BAR;                                                                       \
    _Pragma("unroll") for (int j = 2; j < 4; j++) {                            \
      bF[j][0] = RB(BB, j, 0); bF[j][1] = RB(BB, j, 1);                        \
    }                                                                          \
    STG((SB) + 16384, gB + 131072, kk);                                        \
    BAR; LGKM0;                                                                \
    __builtin_amdgcn_s_setprio(1);                                             \
    _Pragma("unroll") for (int i = 0; i < 4; i++) {                            \
      _Pragma("unroll") for (int j = 2; j < 4; j++) {                          \
        MM(acc[i][j], aF[i][0], bF[j][0]); MM(acc[i][j], aF[i][1], bF[j][1]);  \
      }                                                                        \
    }                                                                          \
    __builtin_amdgcn_s_setprio(0);                                             \
    VM6; BAR;                                                                  \
  } while (0)

  // prologue: stage tiles 0,1 (6 instrs each); VM6 -> tile0 landed, tile1 flying
  STG(0, gA, 0);
  STG(49152, gB, 0);
  STG(49152 + 16384, gB + 131072, 0);
  STG(16384, gA, 1);
  STG(81920, gB, 1);
  STG(81920 + 16384, gB + 131072, 1);
  VM6;
  BAR;

#pragma unroll 1
  for (int tt = 0; tt < 15; tt += 3) {
    TILE(0, 49152, 32768, 114688, tt + 2);                        // t=tt:   rb0 -> sb2
    TILE(16384, 81920, 0, 49152, tt + 3);                         // t=tt+1: rb1 -> sb0
    TILE(32768, 114688, 16384, 81920, (tt + 4 > 15 ? 15 : tt + 4));  // t=tt+2: rb2 -> sb1
  }
  TILE(0, 49152, 32768, 114688, 15);  // t=15: rb0; clamped stage -> dead buf2
#undef STG
#undef RA
#undef RB
#undef BAR
#undef LGKM0
#undef VM6
#undef MM
#undef TILE

  // ---- epilogue: drain pipeline ----
  asm volatile("s_waitcnt vmcnt(0) lgkmcnt(0)" ::: "memory");
  const int lrw = wm * 16 + (lane >> 4) * 4;  // LDS row base for C writes (0..31)
  const int lcw = wn * 64 + (lane & 15);
  const int er = tid >> 4, ec = (tid & 15) * 16;  // reader: 32 rows x 16 chunks
  const int growb = m0 + (er >> 4) * 64 + (er & 15);
  float bi[4];
#pragma unroll
  for (int j = 0; j < 4; j++) bi[j] = bias[n0 + wn * 64 + j * 16 + (lane & 15)];
  if (EPI == 1) {
    const int seg = n0 >> 10;  // 256 | 1024 -> block-uniform segment
    unsigned short* dst = (seg == 0) ? o_inp : (seg == 1) ? o_og : o_om;
    unsigned short* Cs = (unsigned short*)smem;  // 32 x 264 bf16 per group
    float Lv[4];
#pragma unroll
    for (int j = 0; j < 4; j++)
      Lv[j] = (seg == 2) ? lb[(n0 + wn * 64 + j * 16 + (lane & 15)) & 1023] : 0.f;
#pragma unroll
    for (int i = 0; i < 4; i++) {
      __syncthreads();
#pragma unroll
      for (int j = 0; j < 4; j++)
#pragma unroll
        for (int g = 0; g < 4; g++) {
          float v = acc[i][j][g] + bi[j];
          unsigned short ob;
          if (seg == 0) { float s = 1.f / (1.f + __expf(-v)); ob = f2bf(v * s); }
          else if (seg == 1) { float s = 1.f / (1.f + __expf(-v)); ob = f2bf(s); }
          else { float sm = 1.f / (1.f + __expf(v)); ob = f2bf((1.f - Lv[j]) * sm); }
          Cs[(lrw + g) * 264 + lcw + j * 16] = ob;
        }
      __syncthreads();
      uint4 v0 = *(uint4*)&Cs[er * 264 + ec];
      uint4 v1 = *(uint4*)&Cs[er * 264 + ec + 8];
      size_t ro = (size_t)(growb + i * 16) * 1024 + (n0 & 1023) + ec;
      *(uint4*)&dst[ro] = v0;
      *(uint4*)&dst[ro + 8] = v1;
    }
  } else {
    float* Cf = (float*)smem;  // 32 x 264 fp32 per group (33.8KB)
#pragma unroll
    for (int i = 0; i < 4; i++) {
      __syncthreads();
#pragma unroll
      for (int j = 0; j < 4; j++)
#pragma unroll
        for (int g = 0; g < 4; g++)
          Cf[(lrw + g) * 264 + lcw + j * 16] = acc[i][j][g] + bi[j];
      __syncthreads();
      size_t ro = (size_t)(growb + i * 16) * 1024 + n0 + ec;
#pragma unroll
      for (int k = 0; k < 4; k++) {
        float4 v = *(float4*)&Cf[er * 264 + ec + k * 4];
        *(float4*)&outf[ro + k * 4] = v;
      }
    }
  }
}

// ---------------- chunked bidirectional scan ----------------
__global__ void scan_passA(const unsigned short* __restrict__ om, const unsigned short* __restrict__ ip,
                           float* __restrict__ sumA, float* __restrict__ sumBf,
                           float* __restrict__ sumBr) {
  int idx = blockIdx.x * 256 + threadIdx.x;
  int h = idx & 511, cb = idx >> 9, b = cb & 3, c = cb >> 2;
  long base = ((long)c * CLEN * 4 + b) * 1024 + 2 * h;
  float p0 = 1.f, p1 = 1.f;
  float s00 = 0.f, s01 = 0.f, s10 = 0.f, s11 = 0.f;
  float r00 = 0.f, r01 = 0.f, r10 = 0.f, r11 = 0.f;
#pragma unroll
  for (int t = 0; t < CLEN; t++) {
    ushort2 l2 = *(const ushort2*)(om + base);
    ushort2 i2 = *(const ushort2*)(ip + base);
    base += 4096;
    float omx = bf2f(l2.x), omy = bf2f(l2.y);
    float ipx = bf2f(i2.x), ipy = bf2f(i2.y);
    float lx = 1.f - omx, ly = 1.f - omy;
    float u00 = omx * ipx, u01 = omx * ipy, u10 = omy * ipx, u11 = omy * ipy;
    r00 += p0 * u00; r01 += p0 * u01; r10 += p1 * u10; r11 += p1 * u11;
    s00 = lx * s00 + u00; s01 = lx * s01 + u01;
    s10 = ly * s10 + u10; s11 = ly * s11 + u11;
    p0 *= lx; p1 *= ly;
  }
  ((float2*)sumA)[idx] = make_float2(p0, p1);
  ((float4*)sumBf)[idx] = make_float4(s00, s01, s10, s11);
  ((float4*)sumBr)[idx] = make_float4(r00, r01, r10, r11);
}

// ---- passB parallelized: two-level scan over 128 chunks (8 super x 16) ----
__global__ void scan_b1(const float* __restrict__ sumA, const float* __restrict__ sumBf,
                        const float* __restrict__ sumBr,
                        float* __restrict__ superA, float* __restrict__ superB) {
  int t = blockIdx.x * 256 + threadIdx.x;  // 131072
  int ch = t & 3, bh = (t >> 2) & 2047, sc = (t >> 13) & 7, dir = t >> 16;
  int dd = ch >> 1;
  float Acc = 1.f, Bcc = 0.f;
  if (dir == 0) {
    for (int i = 0; i < 16; i++) {
      int si = (sc * 16 + i) * 2048 + bh;
      float a = sumA[(size_t)si * 2 + dd];
      float b = sumBf[(size_t)si * 4 + ch];
      Bcc = a * Bcc + b;
      Acc *= a;
    }
  } else {
    for (int i = 15; i >= 0; i--) {
      int si = (sc * 16 + i) * 2048 + bh;
      float a = sumA[(size_t)si * 2 + dd];
      float b = sumBr[(size_t)si * 4 + ch];
      Bcc = a * Bcc + b;
      Acc *= a;
    }
  }
  superA[t] = Acc;
  superB[t] = Bcc;
}

__global__ void scan_b2(const float* __restrict__ superA, const float* __restrict__ superB,
                        float* __restrict__ SI) {
  int t = blockIdx.x * 256 + threadIdx.x;  // 16384
  int ch = t & 3, bh = (t >> 2) & 2047, dir = t >> 13;
  float H = 0.f;
  if (dir == 0) {
    for (int sc = 0; sc < 8; sc++) {
      size_t idx = ((size_t)(dir * 8 + sc) * 2048 + bh) * 4 + ch;
      SI[idx] = H;
      H = superA[idx] * H + superB[idx];
    }
  } else {
    for (int sc = 7; sc >= 0; sc--) {
      size_t idx = ((size_t)(dir * 8 + sc) * 2048 + bh) * 4 + ch;
      SI[idx] = H;
      H = superA[idx] * H + superB[idx];
    }
  }
}

__global__ void scan_b3(const float* __restrict__ sumA, const float* __restrict__ sumBf,
                        const float* __restrict__ sumBr, const float* __restrict__ SI,
                        float* __restrict__ initF, float* __restrict__ initR) {
  int t = blockIdx.x * 256 + threadIdx.x;  // 131072
  int ch = t & 3, bh = (t >> 2) & 2047, sc = (t >> 13) & 7, dir = t >> 16;
  int dd = ch >> 1;
  float H = SI[t];
  if (dir == 0) {
    for (int i = 0; i < 16; i++) {
      int si = (sc * 16 + i) * 2048 + bh;
      initF[(size_t)si * 4 + ch] = H;
      H = sumA[(size_t)si * 2 + dd] * H + sumBf[(size_t)si * 4 + ch];
    }
  } else {
    for (int i = 15; i >= 0; i--) {
      int si = (sc * 16 + i) * 2048 + bh;
      initR[(size_t)si * 4 + ch] = H;
      H = sumA[(size_t)si * 2 + dd] * H + sumBr[(size_t)si * 4 + ch];
    }
  }
}

// ---- fused replay (fwd+rev) + layernorm -> bf16 y ----
__global__ __launch_bounds__(512) void scanC_ln_kernel(
    const unsigned short* __restrict__ om, const unsigned short* __restrict__ ip,
    const unsigned short* __restrict__ og,
    const float* __restrict__ initF, const float* __restrict__ initR,
    const float* __restrict__ gamma, const float* __restrict__ beta,
    unsigned short* __restrict__ ybf) {
  __shared__ float tile[8][1024];
  __shared__ float ldsG[1024];
  __shared__ float ldsB[1024];
  const int h = threadIdx.x;  // 0..511
  const int cb = blockIdx.x;  // c*4 + b
  const int b = cb & 3, c = cb >> 2;
  const int idx = cb * 512 + h;
  *(float2*)&ldsG[2 * h] = *(const float2*)(gamma + 2 * h);
  *(float2*)&ldsB[2 * h] = *(const float2*)(beta + 2 * h);
  float4 F = ((const float4*)initF)[idx];
  float4 R = ((const float4*)initR)[idx];
  float outx[CLEN], outy[CLEN];
  unsigned int lS[CLEN], iS[CLEN], oS[CLEN];
  const long base = ((long)c * CLEN * 4 + b) * 1024 + 2 * h;
  float h00 = F.x, h01 = F.y, h10 = F.z, h11 = F.w;
  long p = base;
#pragma unroll
  for (int t = 0; t < CLEN; t++) {
    unsigned int l2 = *(const unsigned int*)(om + p);
    unsigned int i2 = *(const unsigned int*)(ip + p);
    unsigned int o2 = *(const unsigned int*)(og + p);
    p += 4096;
    lS[t] = l2; iS[t] = i2; oS[t] = o2;
    float omx = bf2f_lo(l2), omy = bf2f_hi(l2);
    float ipx = bf2f_lo(i2), ipy = bf2f_hi(i2);
    float ox = bf2f_lo(o2), oy = bf2f_hi(o2);
    float lx = 1.f - omx, ly = 1.f - omy;
    h00 = lx * h00 + omx * ipx; h01 = lx * h01 + omx * ipy;
    h10 = ly * h10 + omy * ipx; h11 = ly * h11 + omy * ipy;
    outx[t] = h00 * ox + h10 * oy;
    outy[t] = h01 * ox + h11 * oy;
  }
  float g00 = R.x, g01 = R.y, g10 = R.z, g11 = R.w;
#pragma unroll
  for (int t = CLEN - 1; t >= 0; t--) {
    unsigned int l2 = lS[t], i2 = iS[t], o2 = oS[t];
    float omx = bf2f_lo(l2), omy = bf2f_hi(l2);
    float ipx = bf2f_lo(i2), ipy = bf2f_hi(i2);
    float ox = bf2f_lo(o2), oy = bf2f_hi(o2);
    float lx = 1.f - omx, ly = 1.f - omy;
    g00 = omx * ipx + lx * g00; g01 = omx * ipy + lx * g01;
    g10 = omy * ipx + ly * g10; g11 = omy * ipy + ly * g11;
    outx[t] += g00 * ox + g10 * oy;
    outy[t] += g01 * ox + g11 * oy;
  }
  const int lane = h & 63, wv = h >> 6;
#pragma unroll
  for (int g = 0; g < CLEN / 8; g++) {
    __syncthreads();
#pragma unroll
    for (int r = 0; r < 8; r++) {
      float2 v2 = make_float2(outx[g * 8 + r], outy[g * 8 + r]);
      *(float2*)&tile[r][2 * h] = v2;
    }
    __syncthreads();
    {
      const int t = g * 8 + wv;
      float4 v[4];
#pragma unroll
      for (int k = 0; k < 4; k++) v[k] = *(const float4*)&tile[wv][lane * 16 + k * 4];
      float s = 0.f, s2 = 0.f;
#pragma unroll
      for (int k = 0; k < 4; k++) {
        s += v[k].x + v[k].y + v[k].z + v[k].w;
        s2 += v[k].x * v[k].x + v[k].y * v[k].y + v[k].z * v[k].z + v[k].w * v[k].w;
      }
#pragma unroll
      for (int off = 1; off < 64; off <<= 1) {
        s += __shfl_xor(s, off);
        s2 += __shfl_xor(s2, off);
      }
      float mean = s * (1.f / 1024.f);
      float var = s2 * (1.f / 1024.f) - mean * mean;
      float rstd = rsqrtf(var + 1e-5f);
      unsigned short o16[16];
#pragma unroll
      for (int k = 0; k < 4; k++) {
        float* vv = (float*)&v[k];
#pragma unroll
        for (int e = 0; e < 4; e++) {
          int ch = lane * 16 + k * 4 + e;
          o16[k * 4 + e] = f2bf((vv[e] - mean) * rstd * ldsG[ch] + ldsB[ch]);
        }
      }
      size_t rowo = ((size_t)(c * CLEN + t) * 4 + b) * 1024 + lane * 16;
      *(uint4*)(ybf + rowo) = *(uint4*)&o16[0];
      *(uint4*)(ybf + rowo + 8) = *(uint4*)&o16[8];
    }
  }
}

// ---------------- launch ----------------
extern "C" void kernel_launch(void* const* d_in, const int* in_sizes, int n_in,
                              void* d_out, int out_size, void* d_ws, size_t ws_size,
                              hipStream_t stream) {
  const float* x = (const float*)d_in[0];
  const float* lb = (const float*)d_in[1];
  const float* Win = (const float*)d_in[2];
  const float* bin = (const float*)d_in[3];
  const float* Wout = (const float*)d_in[4];
  const float* bout = (const float*)d_in[5];
  const float* gamma = (const float*)d_in[6];
  const float* beta = (const float*)d_in[7];
  float* out = (float*)d_out;

  char* ws = (char*)d_ws;
  size_t off = 0;
  auto alloc = [&](size_t bytes) {
    void* p = ws + off;
    off += (bytes + 255) & ~(size_t)255;
    return p;
  };
  unsigned short* x_bf = (unsigned short*)alloc(8192ull * 1024 * 2);
  unsigned short* winT = (unsigned short*)alloc(3072ull * 1024 * 2);
  unsigned short* woutT = (unsigned short*)alloc(1024ull * 1024 * 2);
  unsigned short* inp_b = (unsigned short*)alloc(8192ull * 1024 * 2);
  unsigned short* og_b = (unsigned short*)alloc(8192ull * 1024 * 2);
  unsigned short* om_b = (unsigned short*)alloc(8192ull * 1024 * 2);
  unsigned short* y_bf = (unsigned short*)alloc(8192ull * 1024 * 2);
  float* sumA = (float*)alloc((size_t)NCH * 4 * 512 * 2 * 4);
  float* sumBf = (float*)alloc((size_t)NCH * 4 * 512 * 4 * 4);
  float* sumBr = (float*)alloc((size_t)NCH * 4 * 512 * 4 * 4);
  float* initF = (float*)alloc((size_t)NCH * 4 * 512 * 4 * 4);
  float* initR = (float*)alloc((size_t)NCH * 4 * 512 * 4 * 4);
  float* superA = (float*)alloc(131072ull * 4);
  float* superB = (float*)alloc(131072ull * 4);
  float* SIbuf = (float*)alloc(131072ull * 4);

  cast_x_kernel<<<8192, 256, 0, stream>>>(x, x_bf);
  tcast2_kernel<<<dim3(128, 32), dim3(32, 32), 0, stream>>>(Win, winT, Wout, woutT);
  gemm1_kernel<1><<<768, 512, 0, stream>>>(x_bf, winT, bin, lb, nullptr, inp_b, og_b, om_b);
  scan_passA<<<(NCH * 4 * 512) / 256, 256, 0, stream>>>(om_b, inp_b, sumA, sumBf, sumBr);
  scan_b1<<<512, 256, 0, stream>>>(sumA, sumBf, sumBr, superA, superB);
  scan_b2<<<64, 256, 0, stream>>>(superA, superB, SIbuf);
  scan_b3<<<512, 256, 0, stream>>>(sumA, sumBf, sumBr, SIbuf, initF, initR);
  scanC_ln_kernel<<<NCH * 4, 512, 0, stream>>>(om_b, inp_b, og_b, initF, initR, gamma, beta, y_bf);
  gemm1_kernel<0><<<256, 512, 0, stream>>>(y_bf, woutT, bout, nullptr, out, nullptr, nullptr, nullptr);
}

// Round 8
// 239.665 us; speedup vs baseline: 1.0341x; 1.0341x over previous
//
#include <hip/hip_runtime.h>

typedef __bf16 bf16x8 __attribute__((ext_vector_type(8)));
typedef float floatx4 __attribute__((ext_vector_type(4)));

#define NCH 128  // number of time chunks
#define CLEN 16  // chunk length (NCH*CLEN = 2048)

__device__ __forceinline__ unsigned short f2bf(float f) {
  unsigned int u = __builtin_bit_cast(unsigned int, f);
  u += 0x7fff + ((u >> 16) & 1);
  return (unsigned short)(u >> 16);
}
__device__ __forceinline__ float bf2f(unsigned short u) {
  unsigned int v = (unsigned int)u << 16;
  return __builtin_bit_cast(float, v);
}
__device__ __forceinline__ float bf2f_lo(unsigned int u) {
  return __builtin_bit_cast(float, u << 16);
}
__device__ __forceinline__ float bf2f_hi(unsigned int u) {
  return __builtin_bit_cast(float, u & 0xffff0000u);
}

// async 16B global->LDS copy; LDS dest = wave-uniform base + lane*16
__device__ __forceinline__ void async_copy16(const void* g, void* l) {
  __builtin_amdgcn_global_load_lds(
      (const __attribute__((address_space(1))) unsigned int*)g,
      (__attribute__((address_space(3))) unsigned int*)l, 16, 0, 0);
}

// ---------------- prep: x cast + both weight transposes, ONE launch ----------------
// blocks [0,8192): cast x (fp32 -> bf16), 256 thr x float4
// blocks [8192,11264): Win transpose tiles (96 x 32 tiles of 32x32)
// blocks [11264,12288): Wout transpose tiles (32 x 32 tiles)
__global__ void prep_kernel(const float* __restrict__ x, unsigned short* __restrict__ x_bf,
                            const float* __restrict__ Win, unsigned short* __restrict__ winT,
                            const float* __restrict__ Wout, unsigned short* __restrict__ woutT) {
  __shared__ float tile[32][33];
  const int bx = blockIdx.x;
  const int tid = threadIdx.x;
  if (bx < 8192) {
    int i = bx * 256 + tid;
    float4 v = ((const float4*)x)[i];
    ushort4 o;
    o.x = f2bf(v.x); o.y = f2bf(v.y); o.z = f2bf(v.z); o.w = f2bf(v.w);
    ((ushort4*)x_bf)[i] = o;
    return;
  }
  const float* W;
  unsigned short* WT;
  int ncols, n0, k0;
  if (bx < 8192 + 3072) {
    int t2 = bx - 8192;
    W = Win; WT = winT; ncols = 3072;
    n0 = (t2 % 96) * 32; k0 = (t2 / 96) * 32;
  } else {
    int t2 = bx - 8192 - 3072;
    W = Wout; WT = woutT; ncols = 1024;
    n0 = (t2 & 31) * 32; k0 = (t2 >> 5) * 32;
  }
  const int tx = tid & 31, tyb = tid >> 5;  // 32 x 8
#pragma unroll
  for (int r = 0; r < 4; r++) {
    int ty = tyb + r * 8;
    tile[ty][tx] = W[(size_t)(k0 + ty) * ncols + n0 + tx];
  }
  __syncthreads();
#pragma unroll
  for (int r = 0; r < 4; r++) {
    int ty = tyb + r * 8;
    WT[(size_t)(n0 + ty) * 1024 + k0 + tx] = f2bf(tile[tx][ty]);
  }
}

// ---------------- unified GEMM: 128x256 tile, triple-buffered, R6 schedule ----------------
// BM=128, BN=256, BK=64, 512 thr (2x4 waves, 64x64 out/wave).
// EPI==1 (gemm1): grid 768 = 64m x 12n (= 3 x 256 CUs, zero tail);
//                 activation epilogue -> bf16 silu/sigmoid/om segments.
// EPI==0 (gemm2): grid 256 = 64m x 4n (= 1.0 blocks/CU, zero tail);
//                 bias epilogue -> fp32 out.
// LDS 144KB: A x3 (16KB) @ 0/16384/32768; B x3 (32KB) @ 49152/81920/114688.
// Tile t reads buf t%3; stages tile t+2 into buf (t+2)%3 (WAR-safe by
// rotation). 6 staging instrs/thread/tile -> steady vmcnt(6) once per tile.
template <int EPI>
__global__ __launch_bounds__(512, 2) void gemm1_kernel(
    const unsigned short* __restrict__ A, const unsigned short* __restrict__ BT,
    const float* __restrict__ bias, const float* __restrict__ lb,
    float* __restrict__ outf,
    unsigned short* __restrict__ o_inp, unsigned short* __restrict__ o_og,
    unsigned short* __restrict__ o_om) {
  __shared__ alignas(16) char smem[147456];
  // XCD-aware bijective swizzle (m-fast: best measured).
  const int orig = blockIdx.x;
  const int wg = (EPI == 1) ? (orig & 7) * 96 + (orig >> 3)   // 768 = 8 x 96
                            : (orig & 7) * 32 + (orig >> 3);  // 256 = 8 x 32
  const int m0 = (wg & 63) << 7;  // 64 m-tiles of 128 (fast -> share B panel)
  const int n0 = (wg >> 6) << 8;  // 12 (EPI=1) / 4 (EPI=0) n-tiles of 256
  const int tid = threadIdx.x;
  const int lane = tid & 63, wave = tid >> 6;
  const int wm = wave >> 2, wn = wave & 3;
  // staging: thread covers LDS slot (row=tid>>3, chunk=tid&7); fetch global
  // chunk (tid&7)^(row&7) so linear global_load_lds realizes the swizzle
  const int srow = tid >> 3;
  const int sq = (tid & 7) ^ (srow & 7);
  const unsigned short* gA = A + (size_t)(m0 + srow) * 1024 + sq * 8;
  const unsigned short* gB = BT + (size_t)(n0 + srow) * 1024 + sq * 8;
  char* lw = smem + wave * 1024;  // wave-uniform LDS slot base
  // ds_read: row r at byte r*128; chunk q at (q^(r&7))*16; r&7 == lane&7 here
  const int aro = (wm * 64 + (lane & 15)) * 128;
  const int bro = (wn * 64 + (lane & 15)) * 128;
  const int qs0 = ((lane >> 4) ^ (lane & 7)) * 16;        // k-step 0 (k 0..31)
  const int qs1 = ((4 + (lane >> 4)) ^ (lane & 7)) * 16;  // k-step 1 (k 32..63)

  floatx4 acc[4][4] = {};
  bf16x8 aF[4][2], bF[4][2];

#define STG(lofs, gh, kk)                                \
  do {                                                   \
    const unsigned short* _g = (gh) + (size_t)(kk) * 64; \
    async_copy16(_g, lw + (lofs));                       \
    async_copy16(_g + 65536, lw + (lofs) + 8192);        \
  } while (0)
#define RA(base, i, s) \
  (*(const bf16x8*)(smem + (base) + aro + (i) * 2048 + ((s) ? qs1 : qs0)))
#define RB(base, j, s) \
  (*(const bf16x8*)(smem + (base) + bro + (j) * 2048 + ((s) ? qs1 : qs0)))
#define BAR __builtin_amdgcn_s_barrier()
#define LGKM0 asm volatile("s_waitcnt lgkmcnt(0)" ::: "memory")
#define VM6 asm volatile("s_waitcnt vmcnt(6)" ::: "memory")
#define MM(d, a, b) d = __builtin_amdgcn_mfma_f32_16x16x32_bf16(a, b, d, 0, 0, 0)

// One K-tile: Phase A (A reads + B01 + stage A[t+2],B[t+2]h0 -> MFMA j01),
// Phase B (B23 reads + stage B[t+2]h1 -> MFMA j23, vmcnt(6)).
#define TILE(AB, BB, SA, SB, kk)                                               \
  do {                                                                         \
    _Pragma("unroll") for (int i = 0; i < 4; i++) {                            \
      aF[i][0] = RA(AB, i, 0); aF[i][1] = RA(AB, i, 1);                        \
    }                                                                          \
    _Pragma("unroll") for (int j = 0; j < 2; j++) {                            \
      bF[j][0] = RB(BB, j, 0); bF[j][1] = RB(BB, j, 1);                        \
    }                                                                          \
    STG(SA, gA, kk);                                                           \
    STG(SB, gB, kk);                                                           \
    BAR; LGKM0;                                                                \
    __builtin_amdgcn_s_setprio(1);                                             \
    _Pragma("unroll") for (int i = 0; i < 4; i++) {                            \
      _Pragma("unroll") for (int j = 0; j < 2; j++) {                          \
        MM(acc[i][j], aF[i][0], bF[j][0]); MM(acc[i][j], aF[i][1], bF[j][1]);  \
      }                                                                        \
    }                                                                          \
    __builtin_amdgcn_s_setprio(0);                                             \
    BAR;                                                                       \
    _Pragma("unroll") for (int j = 2; j < 4; j++) {                            \
      bF[j][0] = RB(BB, j, 0); bF[j][1] = RB(BB, j, 1);                        \
    }                                                                          \
    STG((SB) + 16384, gB + 131072, kk);                                        \
    BAR; LGKM0;                                                                \
    __builtin_amdgcn_s_setprio(1);                                             \
    _Pragma("unroll") for (int i = 0; i < 4; i++) {                            \
      _Pragma("unroll") for (int j = 2; j < 4; j++) {                          \
        MM(acc[i][j], aF[i][0], bF[j][0]); MM(acc[i][j], aF[i][1], bF[j][1]);  \
      }                                                                        \
    }                                                                          \
    __builtin_amdgcn_s_setprio(0);                                             \
    VM6; BAR;                                                                  \
  } while (0)

  // prologue: stage tiles 0,1 (6 instrs each); VM6 -> tile0 landed, tile1 flying
  STG(0, gA, 0);
  STG(49152, gB, 0);
  STG(49152 + 16384, gB + 131072, 0);
  STG(16384, gA, 1);
  STG(81920, gB, 1);
  STG(81920 + 16384, gB + 131072, 1);
  VM6;
  BAR;

#pragma unroll 1
  for (int tt = 0; tt < 15; tt += 3) {
    TILE(0, 49152, 32768, 114688, tt + 2);                        // t=tt:   rb0 -> sb2
    TILE(16384, 81920, 0, 49152, tt + 3);                         // t=tt+1: rb1 -> sb0
    TILE(32768, 114688, 16384, 81920, (tt + 4 > 15 ? 15 : tt + 4));  // t=tt+2: rb2 -> sb1
  }
  TILE(0, 49152, 32768, 114688, 15);  // t=15: rb0; clamped stage -> dead buf2
#undef STG
#undef RA
#undef RB
#undef BAR
#undef LGKM0
#undef VM6
#undef MM
#undef TILE

  // ---- epilogue: drain pipeline ----
  asm volatile("s_waitcnt vmcnt(0) lgkmcnt(0)" ::: "memory");
  const int lrw = wm * 16 + (lane >> 4) * 4;  // LDS row base for C writes (0..31)
  const int lcw = wn * 64 + (lane & 15);
  const int er = tid >> 4, ec = (tid & 15) * 16;  // reader: 32 rows x 16 chunks
  const int growb = m0 + (er >> 4) * 64 + (er & 15);
  float bi[4];
#pragma unroll
  for (int j = 0; j < 4; j++) bi[j] = bias[n0 + wn * 64 + j * 16 + (lane & 15)];
  if (EPI == 1) {
    const int seg = n0 >> 10;  // 256 | 1024 -> block-uniform segment
    unsigned short* dst = (seg == 0) ? o_inp : (seg == 1) ? o_og : o_om;
    unsigned short* Cs = (unsigned short*)smem;  // 32 x 264 bf16 per group
    float Lv[4];
#pragma unroll
    for (int j = 0; j < 4; j++)
      Lv[j] = (seg == 2) ? lb[(n0 + wn * 64 + j * 16 + (lane & 15)) & 1023] : 0.f;
#pragma unroll
    for (int i = 0; i < 4; i++) {
      __syncthreads();
#pragma unroll
      for (int j = 0; j < 4; j++)
#pragma unroll
        for (int g = 0; g < 4; g++) {
          float v = acc[i][j][g] + bi[j];
          unsigned short ob;
          if (seg == 0) { float s = 1.f / (1.f + __expf(-v)); ob = f2bf(v * s); }
          else if (seg == 1) { float s = 1.f / (1.f + __expf(-v)); ob = f2bf(s); }
          else { float sm = 1.f / (1.f + __expf(v)); ob = f2bf((1.f - Lv[j]) * sm); }
          Cs[(lrw + g) * 264 + lcw + j * 16] = ob;
        }
      __syncthreads();
      uint4 v0 = *(uint4*)&Cs[er * 264 + ec];
      uint4 v1 = *(uint4*)&Cs[er * 264 + ec + 8];
      size_t ro = (size_t)(growb + i * 16) * 1024 + (n0 & 1023) + ec;
      *(uint4*)&dst[ro] = v0;
      *(uint4*)&dst[ro + 8] = v1;
    }
  } else {
    float* Cf = (float*)smem;  // 32 x 264 fp32 per group (33.8KB)
#pragma unroll
    for (int i = 0; i < 4; i++) {
      __syncthreads();
#pragma unroll
      for (int j = 0; j < 4; j++)
#pragma unroll
        for (int g = 0; g < 4; g++)
          Cf[(lrw + g) * 264 + lcw + j * 16] = acc[i][j][g] + bi[j];
      __syncthreads();
      size_t ro = (size_t)(growb + i * 16) * 1024 + n0 + ec;
#pragma unroll
      for (int k = 0; k < 4; k++) {
        float4 v = *(float4*)&Cf[er * 264 + ec + k * 4];
        *(float4*)&outf[ro + k * 4] = v;
      }
    }
  }
}

// ---------------- chunked bidirectional scan ----------------
__global__ void scan_passA(const unsigned short* __restrict__ om, const unsigned short* __restrict__ ip,
                           float* __restrict__ sumA, float* __restrict__ sumBf,
                           float* __restrict__ sumBr) {
  int idx = blockIdx.x * 256 + threadIdx.x;
  int h = idx & 511, cb = idx >> 9, b = cb & 3, c = cb >> 2;
  long base = ((long)c * CLEN * 4 + b) * 1024 + 2 * h;
  float p0 = 1.f, p1 = 1.f;
  float s00 = 0.f, s01 = 0.f, s10 = 0.f, s11 = 0.f;
  float r00 = 0.f, r01 = 0.f, r10 = 0.f, r11 = 0.f;
#pragma unroll
  for (int t = 0; t < CLEN; t++) {
    ushort2 l2 = *(const ushort2*)(om + base);
    ushort2 i2 = *(const ushort2*)(ip + base);
    base += 4096;
    float omx = bf2f(l2.x), omy = bf2f(l2.y);
    float ipx = bf2f(i2.x), ipy = bf2f(i2.y);
    float lx = 1.f - omx, ly = 1.f - omy;
    float u00 = omx * ipx, u01 = omx * ipy, u10 = omy * ipx, u11 = omy * ipy;
    r00 += p0 * u00; r01 += p0 * u01; r10 += p1 * u10; r11 += p1 * u11;
    s00 = lx * s00 + u00; s01 = lx * s01 + u01;
    s10 = ly * s10 + u10; s11 = ly * s11 + u11;
    p0 *= lx; p1 *= ly;
  }
  ((float2*)sumA)[idx] = make_float2(p0, p1);
  ((float4*)sumBf)[idx] = make_float4(s00, s01, s10, s11);
  ((float4*)sumBr)[idx] = make_float4(r00, r01, r10, r11);
}

// ---- passB parallelized: two-level scan over 128 chunks (8 super x 16) ----
// B1: per (dir,sc,bh,ch) compose chunks of superchunk sc -> (superA,superB)
__global__ void scan_b1(const float* __restrict__ sumA, const float* __restrict__ sumBf,
                        const float* __restrict__ sumBr,
                        float* __restrict__ superA, float* __restrict__ superB) {
  int t = blockIdx.x * 256 + threadIdx.x;  // 131072
  int ch = t & 3, bh = (t >> 2) & 2047, sc = (t >> 13) & 7, dir = t >> 16;
  int dd = ch >> 1;
  float Acc = 1.f, Bcc = 0.f;
  if (dir == 0) {
    for (int i = 0; i < 16; i++) {
      int si = (sc * 16 + i) * 2048 + bh;
      float a = sumA[(size_t)si * 2 + dd];
      float b = sumBf[(size_t)si * 4 + ch];
      Bcc = a * Bcc + b;
      Acc *= a;
    }
  } else {
    for (int i = 15; i >= 0; i--) {
      int si = (sc * 16 + i) * 2048 + bh;
      float a = sumA[(size_t)si * 2 + dd];
      float b = sumBr[(size_t)si * 4 + ch];
      Bcc = a * Bcc + b;
      Acc *= a;
    }
  }
  superA[t] = Acc;
  superB[t] = Bcc;
}

// B3 (absorbs old B2): per (dir,sc,bh,ch) compute superchunk prefix inline
// (sc is block-uniform -> no divergence; composition order identical to the
// old b2, so results are bit-identical), then fill per-chunk inits.
__global__ void scan_b3(const float* __restrict__ sumA, const float* __restrict__ sumBf,
                        const float* __restrict__ sumBr,
                        const float* __restrict__ superA, const float* __restrict__ superB,
                        float* __restrict__ initF, float* __restrict__ initR) {
  int t = blockIdx.x * 256 + threadIdx.x;  // 131072
  int ch = t & 3, bh = (t >> 2) & 2047, sc = (t >> 13) & 7, dir = t >> 16;
  int dd = ch >> 1;
  float H = 0.f;
  if (dir == 0) {
    for (int s = 0; s < sc; s++) {
      size_t idx = ((size_t)s * 2048 + bh) * 4 + ch;
      H = superA[idx] * H + superB[idx];
    }
    for (int i = 0; i < 16; i++) {
      int si = (sc * 16 + i) * 2048 + bh;
      initF[(size_t)si * 4 + ch] = H;
      H = sumA[(size_t)si * 2 + dd] * H + sumBf[(size_t)si * 4 + ch];
    }
  } else {
    for (int s = 7; s > sc; s--) {
      size_t idx = ((size_t)(8 + s) * 2048 + bh) * 4 + ch;
      H = superA[idx] * H + superB[idx];
    }
    for (int i = 15; i >= 0; i--) {
      int si = (sc * 16 + i) * 2048 + bh;
      initR[(size_t)si * 4 + ch] = H;
      H = sumA[(size_t)si * 2 + dd] * H + sumBr[(size_t)si * 4 + ch];
    }
  }
}

// ---- fused replay (fwd+rev) + layernorm -> bf16 y ----
__global__ __launch_bounds__(512) void scanC_ln_kernel(
    const unsigned short* __restrict__ om, const unsigned short* __restrict__ ip,
    const unsigned short* __restrict__ og,
    const float* __restrict__ initF, const float* __restrict__ initR,
    const float* __restrict__ gamma, const float* __restrict__ beta,
    unsigned short* __restrict__ ybf) {
  __shared__ float tile[8][1024];
  __shared__ float ldsG[1024];
  __shared__ float ldsB[1024];
  const int h = threadIdx.x;  // 0..511
  const int cb = blockIdx.x;  // c*4 + b
  const int b = cb & 3, c = cb >> 2;
  const int idx = cb * 512 + h;
  *(float2*)&ldsG[2 * h] = *(const float2*)(gamma + 2 * h);
  *(float2*)&ldsB[2 * h] = *(const float2*)(beta + 2 * h);
  float4 F = ((const float4*)initF)[idx];
  float4 R = ((const float4*)initR)[idx];
  float outx[CLEN], outy[CLEN];
  unsigned int lS[CLEN], iS[CLEN], oS[CLEN];
  const long base = ((long)c * CLEN * 4 + b) * 1024 + 2 * h;
  float h00 = F.x, h01 = F.y, h10 = F.z, h11 = F.w;
  long p = base;
#pragma unroll
  for (int t = 0; t < CLEN; t++) {
    unsigned int l2 = *(const unsigned int*)(om + p);
    unsigned int i2 = *(const unsigned int*)(ip + p);
    unsigned int o2 = *(const unsigned int*)(og + p);
    p += 4096;
    lS[t] = l2; iS[t] = i2; oS[t] = o2;
    float omx = bf2f_lo(l2), omy = bf2f_hi(l2);
    float ipx = bf2f_lo(i2), ipy = bf2f_hi(i2);
    float ox = bf2f_lo(o2), oy = bf2f_hi(o2);
    float lx = 1.f - omx, ly = 1.f - omy;
    h00 = lx * h00 + omx * ipx; h01 = lx * h01 + omx * ipy;
    h10 = ly * h10 + omy * ipx; h11 = ly * h11 + omy * ipy;
    outx[t] = h00 * ox + h10 * oy;
    outy[t] = h01 * ox + h11 * oy;
  }
  float g00 = R.x, g01 = R.y, g10 = R.z, g11 = R.w;
#pragma unroll
  for (int t = CLEN - 1; t >= 0; t--) {
    unsigned int l2 = lS[t], i2 = iS[t], o2 = oS[t];
    float omx = bf2f_lo(l2), omy = bf2f_hi(l2);
    float ipx = bf2f_lo(i2), ipy = bf2f_hi(i2);
    float ox = bf2f_lo(o2), oy = bf2f_hi(o2);
    float lx = 1.f - omx, ly = 1.f - omy;
    g00 = omx * ipx + lx * g00; g01 = omx * ipy + lx * g01;
    g10 = omy * ipx + ly * g10; g11 = omy * ipy + ly * g11;
    outx[t] += g00 * ox + g10 * oy;
    outy[t] += g01 * ox + g11 * oy;
  }
  const int lane = h & 63, wv = h >> 6;
#pragma unroll
  for (int g = 0; g < CLEN / 8; g++) {
    __syncthreads();
#pragma unroll
    for (int r = 0; r < 8; r++) {
      float2 v2 = make_float2(outx[g * 8 + r], outy[g * 8 + r]);
      *(float2*)&tile[r][2 * h] = v2;
    }
    __syncthreads();
    {
      const int t = g * 8 + wv;
      float4 v[4];
#pragma unroll
      for (int k = 0; k < 4; k++) v[k] = *(const float4*)&tile[wv][lane * 16 + k * 4];
      float s = 0.f, s2 = 0.f;
#pragma unroll
      for (int k = 0; k < 4; k++) {
        s += v[k].x + v[k].y + v[k].z + v[k].w;
        s2 += v[k].x * v[k].x + v[k].y * v[k].y + v[k].z * v[k].z + v[k].w * v[k].w;
      }
#pragma unroll
      for (int off = 1; off < 64; off <<= 1) {
        s += __shfl_xor(s, off);
        s2 += __shfl_xor(s2, off);
      }
      float mean = s * (1.f / 1024.f);
      float var = s2 * (1.f / 1024.f) - mean * mean;
      float rstd = rsqrtf(var + 1e-5f);
      unsigned short o16[16];
#pragma unroll
      for (int k = 0; k < 4; k++) {
        float* vv = (float*)&v[k];
#pragma unroll
        for (int e = 0; e < 4; e++) {
          int ch = lane * 16 + k * 4 + e;
          o16[k * 4 + e] = f2bf((vv[e] - mean) * rstd * ldsG[ch] + ldsB[ch]);
        }
      }
      size_t rowo = ((size_t)(c * CLEN + t) * 4 + b) * 1024 + lane * 16;
      *(uint4*)(ybf + rowo) = *(uint4*)&o16[0];
      *(uint4*)(ybf + rowo + 8) = *(uint4*)&o16[8];
    }
  }
}

// ---------------- launch ----------------
extern "C" void kernel_launch(void* const* d_in, const int* in_sizes, int n_in,
                              void* d_out, int out_size, void* d_ws, size_t ws_size,
                              hipStream_t stream) {
  const float* x = (const float*)d_in[0];
  const float* lb = (const float*)d_in[1];
  const float* Win = (const float*)d_in[2];
  const float* bin = (const float*)d_in[3];
  const float* Wout = (const float*)d_in[4];
  const float* bout = (const float*)d_in[5];
  const float* gamma = (const float*)d_in[6];
  const float* beta = (const float*)d_in[7];
  float* out = (float*)d_out;

  char* ws = (char*)d_ws;
  size_t off = 0;
  auto alloc = [&](size_t bytes) {
    void* p = ws + off;
    off += (bytes + 255) & ~(size_t)255;
    return p;
  };
  unsigned short* x_bf = (unsigned short*)alloc(8192ull * 1024 * 2);
  unsigned short* winT = (unsigned short*)alloc(3072ull * 1024 * 2);
  unsigned short* woutT = (unsigned short*)alloc(1024ull * 1024 * 2);
  unsigned short* inp_b = (unsigned short*)alloc(8192ull * 1024 * 2);
  unsigned short* og_b = (unsigned short*)alloc(8192ull * 1024 * 2);
  unsigned short* om_b = (unsigned short*)alloc(8192ull * 1024 * 2);
  unsigned short* y_bf = (unsigned short*)alloc(8192ull * 1024 * 2);
  float* sumA = (float*)alloc((size_t)NCH * 4 * 512 * 2 * 4);
  float* sumBf = (float*)alloc((size_t)NCH * 4 * 512 * 4 * 4);
  float* sumBr = (float*)alloc((size_t)NCH * 4 * 512 * 4 * 4);
  float* initF = (float*)alloc((size_t)NCH * 4 * 512 * 4 * 4);
  float* initR = (float*)alloc((size_t)NCH * 4 * 512 * 4 * 4);
  float* superA = (float*)alloc(131072ull * 4);
  float* superB = (float*)alloc(131072ull * 4);

  prep_kernel<<<12288, 256, 0, stream>>>(x, x_bf, Win, winT, Wout, woutT);
  gemm1_kernel<1><<<768, 512, 0, stream>>>(x_bf, winT, bin, lb, nullptr, inp_b, og_b, om_b);
  scan_passA<<<(NCH * 4 * 512) / 256, 256, 0, stream>>>(om_b, inp_b, sumA, sumBf, sumBr);
  scan_b1<<<512, 256, 0, stream>>>(sumA, sumBf, sumBr, superA, superB);
  scan_b3<<<512, 256, 0, stream>>>(sumA, sumBf, sumBr, superA, superB, initF, initR);
  scanC_ln_kernel<<<NCH * 4, 512, 0, stream>>>(om_b, inp_b, og_b, initF, initR, gamma, beta, y_bf);
  gemm1_kernel<0><<<256, 512, 0, stream>>>(y_bf, woutT, bout, nullptr, out, nullptr, nullptr, nullptr);
}